// Round 1
// baseline (143.066 us; speedup 1.0000x reference)
//
#include <hip/hip_runtime.h>

// AffineExponential: y = expm(t*W) @ x + bias*t,  ljd = diag(W)*t
// Taylor series of the exponential ACTION on the vector:
//   v_0 = x; v_k = (t/k) * (W @ v_{k-1}); y = sum_k v_k
// ||t*W||_2 <= ~2 (xavier-uniform W, t in [0,1)) -> K=30 terms is overkill-safe.
// fp32 VALU (no fp32 MFMA on CDNA4). Compute-bound: ~2G MAC -> ~26us ideal.

#define DD 128          // feature dim
#define WT_STRIDE 132   // padded LDS stride (floats); 132*4 B, 16B-aligned rows
#define SPB 8           // samples per block
#define KT 30           // Taylor terms

__global__ __launch_bounds__(256, 2)
void affine_exp_kernel(const float* __restrict__ x,
                       const float* __restrict__ t,
                       const float* __restrict__ weight,
                       const float* __restrict__ bias,
                       float* __restrict__ out,
                       int B)
{
    // wt[j*WT_STRIDE + i] = W[i][j]  (transposed so wt[j][i0..i0+3] is contiguous)
    __shared__ float wt[DD * WT_STRIDE];
    __shared__ float vbuf[SPB * DD];

    const int tid = threadIdx.x;

    // Cooperative transposed load of W (one-time; write conflicts tolerable)
    for (int idx = tid; idx < DD * DD; idx += 256) {
        const int i = idx >> 7;         // row of W
        const int j = idx & (DD - 1);   // col of W
        wt[j * WT_STRIDE + i] = weight[idx];
    }

    const int s  = tid >> 5;            // sample slot within block (0..7)
    const int i0 = (tid & 31) << 2;     // this thread's 4 output dims
    const int bs = blockIdx.x * SPB + s;

    const float ts = t[bs];
    const float4 xv = *reinterpret_cast<const float4*>(x + bs * DD + i0);

    float y0 = xv.x, y1 = xv.y, y2 = xv.z, y3 = xv.w;   // k=0 term
    float* vs = vbuf + s * DD;
    *reinterpret_cast<float4*>(vs + i0) = xv;           // v_0 = x
    __syncthreads();   // wt + v visible to all

    for (int k = 1; k <= KT; ++k) {
        float s0 = 0.f, s1 = 0.f, s2 = 0.f, s3 = 0.f;
#pragma unroll
        for (int j = 0; j < DD; j += 4) {
            const float4 vj = *reinterpret_cast<const float4*>(vs + j);
            const float4 wa = *reinterpret_cast<const float4*>(wt + (j + 0) * WT_STRIDE + i0);
            const float4 wb = *reinterpret_cast<const float4*>(wt + (j + 1) * WT_STRIDE + i0);
            const float4 wc = *reinterpret_cast<const float4*>(wt + (j + 2) * WT_STRIDE + i0);
            const float4 wd = *reinterpret_cast<const float4*>(wt + (j + 3) * WT_STRIDE + i0);
            s0 += wa.x * vj.x; s1 += wa.y * vj.x; s2 += wa.z * vj.x; s3 += wa.w * vj.x;
            s0 += wb.x * vj.y; s1 += wb.y * vj.y; s2 += wb.z * vj.y; s3 += wb.w * vj.y;
            s0 += wc.x * vj.z; s1 += wc.y * vj.z; s2 += wc.z * vj.z; s3 += wc.w * vj.z;
            s0 += wd.x * vj.w; s1 += wd.y * vj.w; s2 += wd.z * vj.w; s3 += wd.w * vj.w;
        }
        const float c = ts / (float)k;
        float4 vn;
        vn.x = s0 * c; vn.y = s1 * c; vn.z = s2 * c; vn.w = s3 * c;
        y0 += vn.x; y1 += vn.y; y2 += vn.z; y3 += vn.w;
        __syncthreads();   // everyone done READING v_{k-1}
        *reinterpret_cast<float4*>(vs + i0) = vn;
        __syncthreads();   // v_k visible
    }

    // epilogue: y += bias*t
    const float4 bv = *reinterpret_cast<const float4*>(bias + i0);
    float4 yo;
    yo.x = y0 + bv.x * ts;
    yo.y = y1 + bv.y * ts;
    yo.z = y2 + bv.z * ts;
    yo.w = y3 + bv.w * ts;
    *reinterpret_cast<float4*>(out + (size_t)bs * DD + i0) = yo;

    // ljd = diag(W) * t  (second output, concatenated after y)
    float4 lj;
    lj.x = weight[(i0 + 0) * DD + (i0 + 0)] * ts;
    lj.y = weight[(i0 + 1) * DD + (i0 + 1)] * ts;
    lj.z = weight[(i0 + 2) * DD + (i0 + 2)] * ts;
    lj.w = weight[(i0 + 3) * DD + (i0 + 3)] * ts;
    *reinterpret_cast<float4*>(out + (size_t)B * DD + (size_t)bs * DD + i0) = lj;
}

extern "C" void kernel_launch(void* const* d_in, const int* in_sizes, int n_in,
                              void* d_out, int out_size, void* d_ws, size_t ws_size,
                              hipStream_t stream) {
    const float* x      = (const float*)d_in[0];
    const float* t      = (const float*)d_in[1];
    const float* weight = (const float*)d_in[2];
    const float* bias   = (const float*)d_in[3];
    float* out = (float*)d_out;

    const int B = in_sizes[1];          // t has one scalar per sample
    const int blocks = B / SPB;         // 4096/8 = 512

    affine_exp_kernel<<<blocks, 256, 0, stream>>>(x, t, weight, bias, out, B);
}

// Round 2
// 97.497 us; speedup vs baseline: 1.4674x; 1.4674x over previous
//
#include <hip/hip_runtime.h>

// AffineExponential: y = expm(t*W) @ x + bias*t,  ljd = diag(W)*t
// Taylor action: v_0 = x; v_k = (t/k) * (W v_{k-1}); y = sum v_k.  K=16 terms
// (||tW||<=~2 -> remainder ~4e-10; round-0 passed with 9x margin at fp32).
//
// Round-1 redesign: round 0 was LDS-BW-bound (VALUBusy 33%, ~80 TB/s issued
// LDS reads: full 64KB W re-read per sample per k). Fix: wave = 4 samples,
// lane = 2 dims x 4 samples -> one W sweep serves 4 samples (LDS /4);
// v is wave-private in LDS (broadcast reads, ping-pong buffers, NO barriers
// in the k-loop). K 30->16 halves FLOPs. VALU floor ~14us.

#define DD   128
#define WSTR 132      // wt row stride (floats): hot-loop b64 reads conflict-free
#define KT   16       // Taylor terms
#define SPW  4        // samples per wave
#define NWAVE 4
#define SPB  (SPW * NWAVE)   // 16 samples per block

__global__ __launch_bounds__(256, 1)
void affine_exp_kernel(const float* __restrict__ x,
                       const float* __restrict__ t,
                       const float* __restrict__ weight,
                       const float* __restrict__ bias,
                       float* __restrict__ out,
                       int B)
{
    __shared__ float wt[DD * WSTR];               // wt[j*WSTR+i] = W[i][j]
    __shared__ float vbuf[2][NWAVE][SPW][DD];     // ping-pong, wave-private

    const int tid = threadIdx.x;

    // Stage W transposed (one-time; 8-way write conflicts acceptable)
    for (int idx = tid; idx < DD * DD; idx += 256) {
        const int i = idx >> 7;
        const int j = idx & (DD - 1);
        wt[j * WSTR + i] = weight[idx];
    }

    const int w  = tid >> 6;          // wave id (0..3)
    const int l  = tid & 63;          // lane
    const int i0 = l << 1;            // this lane's 2 dims
    const int s0 = blockIdx.x * SPB + w * SPW;    // wave's first sample

    const float t0 = t[s0 + 0], t1 = t[s0 + 1], t2 = t[s0 + 2], t3 = t[s0 + 3];

    const float2 x0 = *reinterpret_cast<const float2*>(x + (size_t)(s0 + 0) * DD + i0);
    const float2 x1 = *reinterpret_cast<const float2*>(x + (size_t)(s0 + 1) * DD + i0);
    const float2 x2 = *reinterpret_cast<const float2*>(x + (size_t)(s0 + 2) * DD + i0);
    const float2 x3 = *reinterpret_cast<const float2*>(x + (size_t)(s0 + 3) * DD + i0);

    float y00 = x0.x, y01 = x0.y;
    float y10 = x1.x, y11 = x1.y;
    float y20 = x2.x, y21 = x2.y;
    float y30 = x3.x, y31 = x3.y;

    float (*vb0)[DD] = vbuf[0][w];
    float (*vb1)[DD] = vbuf[1][w];

    *reinterpret_cast<float2*>(&vb0[0][i0]) = x0;
    *reinterpret_cast<float2*>(&vb0[1][i0]) = x1;
    *reinterpret_cast<float2*>(&vb0[2][i0]) = x2;
    *reinterpret_cast<float2*>(&vb0[3][i0]) = x3;

    __syncthreads();   // W staged (v writes are wave-private, ordered by lgkmcnt)

    float (*v_rd)[DD] = vb0;
    float (*v_wr)[DD] = vb1;

    for (int k = 1; k <= KT; ++k) {
        float a00 = 0.f, a01 = 0.f, a10 = 0.f, a11 = 0.f;
        float a20 = 0.f, a21 = 0.f, a30 = 0.f, a31 = 0.f;
        const float* v0 = v_rd[0];
        const float* v1 = v_rd[1];
        const float* v2 = v_rd[2];
        const float* v3 = v_rd[3];
#pragma unroll
        for (int j = 0; j < DD; j += 4) {
            const float4 q0 = *reinterpret_cast<const float4*>(v0 + j);  // broadcast
            const float4 q1 = *reinterpret_cast<const float4*>(v1 + j);
            const float4 q2 = *reinterpret_cast<const float4*>(v2 + j);
            const float4 q3 = *reinterpret_cast<const float4*>(v3 + j);
            const float2 w0 = *reinterpret_cast<const float2*>(wt + (j + 0) * WSTR + i0);
            const float2 w1 = *reinterpret_cast<const float2*>(wt + (j + 1) * WSTR + i0);
            const float2 w2 = *reinterpret_cast<const float2*>(wt + (j + 2) * WSTR + i0);
            const float2 w3 = *reinterpret_cast<const float2*>(wt + (j + 3) * WSTR + i0);

            a00 = fmaf(w0.x, q0.x, a00); a00 = fmaf(w1.x, q0.y, a00);
            a00 = fmaf(w2.x, q0.z, a00); a00 = fmaf(w3.x, q0.w, a00);
            a01 = fmaf(w0.y, q0.x, a01); a01 = fmaf(w1.y, q0.y, a01);
            a01 = fmaf(w2.y, q0.z, a01); a01 = fmaf(w3.y, q0.w, a01);

            a10 = fmaf(w0.x, q1.x, a10); a10 = fmaf(w1.x, q1.y, a10);
            a10 = fmaf(w2.x, q1.z, a10); a10 = fmaf(w3.x, q1.w, a10);
            a11 = fmaf(w0.y, q1.x, a11); a11 = fmaf(w1.y, q1.y, a11);
            a11 = fmaf(w2.y, q1.z, a11); a11 = fmaf(w3.y, q1.w, a11);

            a20 = fmaf(w0.x, q2.x, a20); a20 = fmaf(w1.x, q2.y, a20);
            a20 = fmaf(w2.x, q2.z, a20); a20 = fmaf(w3.x, q2.w, a20);
            a21 = fmaf(w0.y, q2.x, a21); a21 = fmaf(w1.y, q2.y, a21);
            a21 = fmaf(w2.y, q2.z, a21); a21 = fmaf(w3.y, q2.w, a21);

            a30 = fmaf(w0.x, q3.x, a30); a30 = fmaf(w1.x, q3.y, a30);
            a30 = fmaf(w2.x, q3.z, a30); a30 = fmaf(w3.x, q3.w, a30);
            a31 = fmaf(w0.y, q3.x, a31); a31 = fmaf(w1.y, q3.y, a31);
            a31 = fmaf(w2.y, q3.z, a31); a31 = fmaf(w3.y, q3.w, a31);
        }
        const float ik = 1.0f / (float)k;
        const float c0 = t0 * ik, c1 = t1 * ik, c2 = t2 * ik, c3 = t3 * ik;
        const float n00 = a00 * c0, n01 = a01 * c0;
        const float n10 = a10 * c1, n11 = a11 * c1;
        const float n20 = a20 * c2, n21 = a21 * c2;
        const float n30 = a30 * c3, n31 = a31 * c3;
        y00 += n00; y01 += n01; y10 += n10; y11 += n11;
        y20 += n20; y21 += n21; y30 += n30; y31 += n31;

        *reinterpret_cast<float2*>(&v_wr[0][i0]) = make_float2(n00, n01);
        *reinterpret_cast<float2*>(&v_wr[1][i0]) = make_float2(n10, n11);
        *reinterpret_cast<float2*>(&v_wr[2][i0]) = make_float2(n20, n21);
        *reinterpret_cast<float2*>(&v_wr[3][i0]) = make_float2(n30, n31);

        float (*tmp)[DD] = v_rd; v_rd = v_wr; v_wr = tmp;
    }

    // epilogue: y += bias*t, store y
    const float2 bv = *reinterpret_cast<const float2*>(bias + i0);
    *reinterpret_cast<float2*>(out + (size_t)(s0 + 0) * DD + i0) =
        make_float2(y00 + bv.x * t0, y01 + bv.y * t0);
    *reinterpret_cast<float2*>(out + (size_t)(s0 + 1) * DD + i0) =
        make_float2(y10 + bv.x * t1, y11 + bv.y * t1);
    *reinterpret_cast<float2*>(out + (size_t)(s0 + 2) * DD + i0) =
        make_float2(y20 + bv.x * t2, y21 + bv.y * t2);
    *reinterpret_cast<float2*>(out + (size_t)(s0 + 3) * DD + i0) =
        make_float2(y30 + bv.x * t3, y31 + bv.y * t3);

    // ljd = diag(W)*t  (wt[j*WSTR+i] = W[i][j] -> diag at i*WSTR+i)
    const float d0 = wt[(size_t)i0 * WSTR + i0];
    const float d1 = wt[(size_t)(i0 + 1) * WSTR + (i0 + 1)];
    float* lout = out + (size_t)B * DD;
    *reinterpret_cast<float2*>(lout + (size_t)(s0 + 0) * DD + i0) = make_float2(d0 * t0, d1 * t0);
    *reinterpret_cast<float2*>(lout + (size_t)(s0 + 1) * DD + i0) = make_float2(d0 * t1, d1 * t1);
    *reinterpret_cast<float2*>(lout + (size_t)(s0 + 2) * DD + i0) = make_float2(d0 * t2, d1 * t2);
    *reinterpret_cast<float2*>(lout + (size_t)(s0 + 3) * DD + i0) = make_float2(d0 * t3, d1 * t3);
}

extern "C" void kernel_launch(void* const* d_in, const int* in_sizes, int n_in,
                              void* d_out, int out_size, void* d_ws, size_t ws_size,
                              hipStream_t stream) {
    const float* x      = (const float*)d_in[0];
    const float* t      = (const float*)d_in[1];
    const float* weight = (const float*)d_in[2];
    const float* bias   = (const float*)d_in[3];
    float* out = (float*)d_out;

    const int B = in_sizes[1];          // one scalar t per sample
    const int blocks = B / SPB;         // 4096/16 = 256

    affine_exp_kernel<<<blocks, 256, 0, stream>>>(x, t, weight, bias, out, B);
}

// Round 3
// 90.196 us; speedup vs baseline: 1.5862x; 1.0809x over previous
//
#include <hip/hip_runtime.h>

// AffineExponential: y = expm(t*W) @ x + bias*t,  ljd = diag(W)*t
// Taylor action: v_0 = x; v_k = (t/k) * (W v_{k-1}); y = sum v_k.  K=12
// (||tW|| <= ~2 -> tail ~1.5e-6, far under fp32 noise 0.016, tol 0.139).
//
// Round-2: S=8 samples share each W-row read (round 1 was LDS-pipe-bound at
// S=4: 2.1KB LDS per 64 VALU cyc). 512 blocks x 4 waves; waves j-split the
// 128-dim reduction 4-ways (32 j each), 2-stage LDS tree reduction per k.
// LDS = 81920 B exactly -> 2 blocks/CU -> 8 waves/CU; co-resident block
// hides barrier stalls. Per j: 1x b128 W-row (half-wave dedup) + 1x b128
// v-broadcast feeding 16 FMA.

#define DD   128
#define WSTR 132      // W^T row stride (floats): staging writes 8-way max, rows 16B-aligned
#define KT   12       // Taylor terms
#define SPB  8        // samples per block
#define JW   32       // j-range per wave

__global__ __launch_bounds__(256, 2)
void affine_exp_kernel(const float* __restrict__ x,
                       const float* __restrict__ t,
                       const float* __restrict__ weight,
                       const float* __restrict__ bias,
                       float* __restrict__ out, int B)
{
    __shared__ float wt[DD * WSTR];     // 67584 B, wt[j*WSTR+i] = W[i][j]
    __shared__ float vq[DD][SPB];       //  4096 B, vq[d][s] = v[s][d]
    __shared__ float red[2][64][20];    // 10240 B, partial-acc buffers (pad 20)

    const int tid = threadIdx.x;
    const int w   = tid >> 6;           // wave 0..3
    const int l   = tid & 63;
    const int h   = l >> 5;             // half: sample group (0: s0..3, 1: s4..7)
    const int q   = l & 31;
    const int i0  = q << 2;             // 4 output dims
    const int s0  = blockIdx.x * SPB;

    // Stage W transposed
    for (int idx = tid; idx < DD * DD; idx += 256) {
        const int i = idx >> 7, j = idx & (DD - 1);
        wt[j * WSTR + i] = weight[idx];
    }
    // Stage v_0 = x  (vq[d][s])
    {
        const int s = tid >> 5, d0 = (tid & 31) << 2;
        const float4 xv = *reinterpret_cast<const float4*>(x + (size_t)(s0 + s) * DD + d0);
        vq[d0 + 0][s] = xv.x; vq[d0 + 1][s] = xv.y;
        vq[d0 + 2][s] = xv.z; vq[d0 + 3][s] = xv.w;
    }
    __syncthreads();

    const float4 tv = *reinterpret_cast<const float4*>(t + s0 + 4 * h);

    // y[d][si] = running Taylor sum for (dim i0+d, sample s0+4h+si); init = v_0
    float y[4][4];
#pragma unroll
    for (int d = 0; d < 4; ++d) {
        const float4 vv = *reinterpret_cast<const float4*>(&vq[i0 + d][4 * h]);
        y[d][0] = vv.x; y[d][1] = vv.y; y[d][2] = vv.z; y[d][3] = vv.w;
    }

    const int j0 = w * JW;
#pragma unroll 1
    for (int k = 1; k <= KT; ++k) {
        float acc[4][4] = {{0.f}};
#pragma unroll
        for (int jj = 0; jj < JW; ++jj) {
            const int j = j0 + jj;
            const float4 wv = *reinterpret_cast<const float4*>(wt + j * WSTR + i0);
            const float4 vv = *reinterpret_cast<const float4*>(&vq[j][4 * h]);
            acc[0][0] = fmaf(wv.x, vv.x, acc[0][0]);
            acc[0][1] = fmaf(wv.x, vv.y, acc[0][1]);
            acc[0][2] = fmaf(wv.x, vv.z, acc[0][2]);
            acc[0][3] = fmaf(wv.x, vv.w, acc[0][3]);
            acc[1][0] = fmaf(wv.y, vv.x, acc[1][0]);
            acc[1][1] = fmaf(wv.y, vv.y, acc[1][1]);
            acc[1][2] = fmaf(wv.y, vv.z, acc[1][2]);
            acc[1][3] = fmaf(wv.y, vv.w, acc[1][3]);
            acc[2][0] = fmaf(wv.z, vv.x, acc[2][0]);
            acc[2][1] = fmaf(wv.z, vv.y, acc[2][1]);
            acc[2][2] = fmaf(wv.z, vv.z, acc[2][2]);
            acc[2][3] = fmaf(wv.z, vv.w, acc[2][3]);
            acc[3][0] = fmaf(wv.w, vv.x, acc[3][0]);
            acc[3][1] = fmaf(wv.w, vv.y, acc[3][1]);
            acc[3][2] = fmaf(wv.w, vv.z, acc[3][2]);
            acc[3][3] = fmaf(wv.w, vv.w, acc[3][3]);
        }

        // Stage 1: w1 -> red[0], w3 -> red[1]
        if (w & 1) {
            float* rb = &red[w >> 1][l][0];
#pragma unroll
            for (int d = 0; d < 4; ++d)
                *reinterpret_cast<float4*>(rb + 4 * d) =
                    make_float4(acc[d][0], acc[d][1], acc[d][2], acc[d][3]);
        }
        __syncthreads();
        if (!(w & 1)) {          // w0 += red[0], w2 += red[1]
            const float* rb = &red[w >> 1][l][0];
#pragma unroll
            for (int d = 0; d < 4; ++d) {
                const float4 p = *reinterpret_cast<const float4*>(rb + 4 * d);
                acc[d][0] += p.x; acc[d][1] += p.y; acc[d][2] += p.z; acc[d][3] += p.w;
            }
        }
        // Stage 2: w2 -> red[1] (reuse after its own read; same-wave DS in-order)
        if (w == 2) {
            float* rb = &red[1][l][0];
#pragma unroll
            for (int d = 0; d < 4; ++d)
                *reinterpret_cast<float4*>(rb + 4 * d) =
                    make_float4(acc[d][0], acc[d][1], acc[d][2], acc[d][3]);
        }
        __syncthreads();
        if (w == 0) {            // finalize: full sum, scale, y +=, write v_k
            const float* rb = &red[1][l][0];
            const float ik = 1.0f / (float)k;
            const float c0 = tv.x * ik, c1 = tv.y * ik, c2 = tv.z * ik, c3 = tv.w * ik;
#pragma unroll
            for (int d = 0; d < 4; ++d) {
                const float4 p = *reinterpret_cast<const float4*>(rb + 4 * d);
                const float n0 = (acc[d][0] + p.x) * c0;
                const float n1 = (acc[d][1] + p.y) * c1;
                const float n2 = (acc[d][2] + p.z) * c2;
                const float n3 = (acc[d][3] + p.w) * c3;
                y[d][0] += n0; y[d][1] += n1; y[d][2] += n2; y[d][3] += n3;
                *reinterpret_cast<float4*>(&vq[i0 + d][4 * h]) = make_float4(n0, n1, n2, n3);
            }
        }
        __syncthreads();
    }

    if (w == 0) {                // y += bias*t, store
        const float4 bv = *reinterpret_cast<const float4*>(bias + i0);
        const float tt[4] = {tv.x, tv.y, tv.z, tv.w};
#pragma unroll
        for (int si = 0; si < 4; ++si) {
            float4 o;
            o.x = y[0][si] + bv.x * tt[si];
            o.y = y[1][si] + bv.y * tt[si];
            o.z = y[2][si] + bv.z * tt[si];
            o.w = y[3][si] + bv.w * tt[si];
            *reinterpret_cast<float4*>(out + (size_t)(s0 + 4 * h + si) * DD + i0) = o;
        }
    }
    if (w == 1) {                // ljd = diag(W) * t
        const float d0 = wt[(i0 + 0) * WSTR + i0 + 0];
        const float d1 = wt[(i0 + 1) * WSTR + i0 + 1];
        const float d2 = wt[(i0 + 2) * WSTR + i0 + 2];
        const float d3 = wt[(i0 + 3) * WSTR + i0 + 3];
        float* lout = out + (size_t)B * DD;
        const float tt[4] = {tv.x, tv.y, tv.z, tv.w};
#pragma unroll
        for (int si = 0; si < 4; ++si)
            *reinterpret_cast<float4*>(lout + (size_t)(s0 + 4 * h + si) * DD + i0) =
                make_float4(d0 * tt[si], d1 * tt[si], d2 * tt[si], d3 * tt[si]);
    }
}

extern "C" void kernel_launch(void* const* d_in, const int* in_sizes, int n_in,
                              void* d_out, int out_size, void* d_ws, size_t ws_size,
                              hipStream_t stream) {
    const float* x      = (const float*)d_in[0];
    const float* t      = (const float*)d_in[1];
    const float* weight = (const float*)d_in[2];
    const float* bias   = (const float*)d_in[3];
    float* out = (float*)d_out;

    const int B = in_sizes[1];          // one scalar t per sample
    const int blocks = B / SPB;         // 4096/8 = 512

    affine_exp_kernel<<<blocks, 256, 0, stream>>>(x, t, weight, bias, out, B);
}

// Round 4
// 67.263 us; speedup vs baseline: 2.1270x; 1.3410x over previous
//
#include <hip/hip_runtime.h>

// AffineExponential: y = expm(t*W) @ x + bias*t,  ljd = diag(W)*t
// Taylor action batched as GEMMs: V_0 = X; V_k = (W V_{k-1}) * diag(t/k);
// y = sum_k V_k. K=12 (||tW|| <= ~2 -> tail ~1e-6).
//
// Round-3 redesign: rounds 0-2 were fp32-VALU/LDS-bound (~41 us). The
// recurrence is matmul-shaped -> MFMA 16x16x32 bf16. Total matrix-pipe work
// is only ~0.2 us/SIMD; kernel is LDS-round-trip/latency bound (~5 us).
// Precision: W = hi + lo bf16 split (2 MFMAs/K-step, ~fp32-accurate W);
// v rounded to bf16 per step (err ~2^-9 rel -> y absmax ~0.03 vs tol 0.139).
// Wave owns 32 rows x 16 samples; W A-frags in 64 VGPRs (loaded once);
// v ping-pongs through 8.7 KB LDS in B-frag layout; 1 barrier per k.

#define DD  128
#define KT  12
#define SPB 16      // samples (columns) per block
#define KS  136     // vs row stride in bf16 elems: 272B = 16B-aligned, bank-spread

typedef short s16x8 __attribute__((ext_vector_type(8)));   // 8 bf16 (4 VGPRs)
typedef short s16x4 __attribute__((ext_vector_type(4)));
typedef float f32x4 __attribute__((ext_vector_type(4)));

__device__ inline unsigned short f2bf(float f) {           // fp32 -> bf16 (RNE)
    unsigned int u = __float_as_uint(f);
    u += 0x7FFFu + ((u >> 16) & 1u);
    return (unsigned short)(u >> 16);
}
__device__ inline float bf2f(unsigned short h) {
    return __uint_as_float(((unsigned int)h) << 16);
}

__global__ __launch_bounds__(256, 1)
void affine_exp_kernel(const float* __restrict__ x,
                       const float* __restrict__ t,
                       const float* __restrict__ weight,
                       const float* __restrict__ bias,
                       float* __restrict__ out, int B)
{
    __shared__ unsigned short vs[2][SPB * KS];   // vs[b][n*KS + k] = bf16 v[k][sample n]

    const int tid = threadIdx.x;
    const int w   = tid >> 6;        // wave 0..3 -> rows [32w, 32w+32)
    const int l   = tid & 63;
    const int n   = l & 15;          // sample / MFMA column
    const int q   = l >> 4;          // quad
    const int s0  = blockIdx.x * SPB;

    const float tn = t[s0 + n];

    // ---- W A-fragments (hi/lo bf16 split), straight from global, once ----
    // A[m = lane&15][k = quad*8 + j]; tile r covers rows 32w+16r+[0,16),
    // kstep s covers k = 32s+[0,32).
    s16x8 wahi[2][4], walo[2][4];
#pragma unroll
    for (int r = 0; r < 2; ++r) {
        const int m = w * 32 + r * 16 + n;
#pragma unroll
        for (int s = 0; s < 4; ++s) {
            const float* wp = weight + (size_t)m * DD + s * 32 + q * 8;
            const f32x4 f0 = *reinterpret_cast<const f32x4*>(wp);
            const f32x4 f1 = *reinterpret_cast<const f32x4*>(wp + 4);
            s16x8 h, lo;
#pragma unroll
            for (int j = 0; j < 4; ++j) {
                const unsigned short hb0 = f2bf(f0[j]);
                const unsigned short hb1 = f2bf(f1[j]);
                h[j]      = (short)hb0;
                h[j + 4]  = (short)hb1;
                lo[j]     = (short)f2bf(f0[j] - bf2f(hb0));
                lo[j + 4] = (short)f2bf(f1[j] - bf2f(hb1));
            }
            wahi[r][s] = h;
            walo[r][s] = lo;
        }
    }

    // ---- y init = v_0 = x, held in MFMA C-layout (col=n, row=q*4+reg) ----
    const int g0 = w * 32 + q * 4;   // r=0 global row base; r=1 adds 16
    f32x4 y0 = *reinterpret_cast<const f32x4*>(x + (size_t)(s0 + n) * DD + g0);
    f32x4 y1 = *reinterpret_cast<const f32x4*>(x + (size_t)(s0 + n) * DD + g0 + 16);

    // ---- stage v_0 = bf16(x), transposed, into vs[0] ----
#pragma unroll
    for (int i = 0; i < 4; ++i) {
        const int d = q * 32 + i * 8;
        const f32x4 a = *reinterpret_cast<const f32x4*>(x + (size_t)(s0 + n) * DD + d);
        const f32x4 b = *reinterpret_cast<const f32x4*>(x + (size_t)(s0 + n) * DD + d + 4);
        s16x8 p;
#pragma unroll
        for (int j = 0; j < 4; ++j) {
            p[j]     = (short)f2bf(a[j]);
            p[j + 4] = (short)f2bf(b[j]);
        }
        *reinterpret_cast<s16x8*>(&vs[0][n * KS + d]) = p;
    }
    __syncthreads();

    // ---- Taylor loop: 1 barrier per k, ping-pong v buffers ----
    int cur = 0;
#pragma unroll
    for (int k = 1; k <= KT; ++k) {
        // B-frags: B[k = s*32 + q*8 + j][n] = vs[cur][n*KS + s*32 + q*8 + j]
        const unsigned short* vp = &vs[cur][n * KS + q * 8];
        const s16x8 vb0 = *reinterpret_cast<const s16x8*>(vp);
        const s16x8 vb1 = *reinterpret_cast<const s16x8*>(vp + 32);
        const s16x8 vb2 = *reinterpret_cast<const s16x8*>(vp + 64);
        const s16x8 vb3 = *reinterpret_cast<const s16x8*>(vp + 96);

        f32x4 a0 = {0.f, 0.f, 0.f, 0.f};
        f32x4 a1 = {0.f, 0.f, 0.f, 0.f};
        a0 = __builtin_amdgcn_mfma_f32_16x16x32_bf16(wahi[0][0], vb0, a0, 0, 0, 0);
        a0 = __builtin_amdgcn_mfma_f32_16x16x32_bf16(walo[0][0], vb0, a0, 0, 0, 0);
        a0 = __builtin_amdgcn_mfma_f32_16x16x32_bf16(wahi[0][1], vb1, a0, 0, 0, 0);
        a0 = __builtin_amdgcn_mfma_f32_16x16x32_bf16(walo[0][1], vb1, a0, 0, 0, 0);
        a0 = __builtin_amdgcn_mfma_f32_16x16x32_bf16(wahi[0][2], vb2, a0, 0, 0, 0);
        a0 = __builtin_amdgcn_mfma_f32_16x16x32_bf16(walo[0][2], vb2, a0, 0, 0, 0);
        a0 = __builtin_amdgcn_mfma_f32_16x16x32_bf16(wahi[0][3], vb3, a0, 0, 0, 0);
        a0 = __builtin_amdgcn_mfma_f32_16x16x32_bf16(walo[0][3], vb3, a0, 0, 0, 0);

        a1 = __builtin_amdgcn_mfma_f32_16x16x32_bf16(wahi[1][0], vb0, a1, 0, 0, 0);
        a1 = __builtin_amdgcn_mfma_f32_16x16x32_bf16(walo[1][0], vb0, a1, 0, 0, 0);
        a1 = __builtin_amdgcn_mfma_f32_16x16x32_bf16(wahi[1][1], vb1, a1, 0, 0, 0);
        a1 = __builtin_amdgcn_mfma_f32_16x16x32_bf16(walo[1][1], vb1, a1, 0, 0, 0);
        a1 = __builtin_amdgcn_mfma_f32_16x16x32_bf16(wahi[1][2], vb2, a1, 0, 0, 0);
        a1 = __builtin_amdgcn_mfma_f32_16x16x32_bf16(walo[1][2], vb2, a1, 0, 0, 0);
        a1 = __builtin_amdgcn_mfma_f32_16x16x32_bf16(wahi[1][3], vb3, a1, 0, 0, 0);
        a1 = __builtin_amdgcn_mfma_f32_16x16x32_bf16(walo[1][3], vb3, a1, 0, 0, 0);

        const float c = tn * (1.0f / (float)k);   // per-lane: col = sample
        a0 *= c;
        a1 *= c;
        y0 += a0;
        y1 += a1;

        // write v_k (bf16) to the other buffer: rows g0..g0+3 and +16
        s16x4 p0, p1;
#pragma unroll
        for (int j = 0; j < 4; ++j) {
            p0[j] = (short)f2bf(a0[j]);
            p1[j] = (short)f2bf(a1[j]);
        }
        unsigned short* wq = &vs[cur ^ 1][n * KS + g0];
        *reinterpret_cast<s16x4*>(wq)      = p0;
        *reinterpret_cast<s16x4*>(wq + 16) = p1;
        __syncthreads();
        cur ^= 1;
    }

    // ---- epilogue: y += bias*t, store (C-layout: lane owns col n, 4+4 rows)
    const f32x4 b0 = *reinterpret_cast<const f32x4*>(bias + g0);
    const f32x4 b1 = *reinterpret_cast<const f32x4*>(bias + g0 + 16);
    y0 += b0 * tn;
    y1 += b1 * tn;
    *reinterpret_cast<f32x4*>(out + (size_t)(s0 + n) * DD + g0)      = y0;
    *reinterpret_cast<f32x4*>(out + (size_t)(s0 + n) * DD + g0 + 16) = y1;

    // ---- ljd = diag(W) * t ----
    {
        const int ns = tid & 15;          // sample
        const int dg = (tid >> 4) * 8;    // dim group
        const float ts = t[s0 + ns];
        f32x4 o0, o1;
#pragma unroll
        for (int j = 0; j < 4; ++j) {
            o0[j] = weight[(size_t)(dg + j) * DD + dg + j] * ts;
            o1[j] = weight[(size_t)(dg + 4 + j) * DD + dg + 4 + j] * ts;
        }
        float* lout = out + (size_t)B * DD + (size_t)(s0 + ns) * DD + dg;
        *reinterpret_cast<f32x4*>(lout)     = o0;
        *reinterpret_cast<f32x4*>(lout + 4) = o1;
    }
}

extern "C" void kernel_launch(void* const* d_in, const int* in_sizes, int n_in,
                              void* d_out, int out_size, void* d_ws, size_t ws_size,
                              hipStream_t stream) {
    const float* x      = (const float*)d_in[0];
    const float* t      = (const float*)d_in[1];
    const float* weight = (const float*)d_in[2];
    const float* bias   = (const float*)d_in[3];
    float* out = (float*)d_out;

    const int B = in_sizes[1];          // one scalar t per sample
    const int blocks = B / SPB;         // 4096/16 = 256

    affine_exp_kernel<<<blocks, 256, 0, stream>>>(x, t, weight, bias, out, B);
}